// Round 6
// baseline (31.411 us; speedup 1.0000x reference)
//
#include <hip/hip_runtime.h>
#include <hip/hip_bf16.h>

#define NUM_SAMPLES 256
#define CH 64
#define IMG_W 512
#define BATCH 8
#define NBLOCKS (BATCH * NUM_SAMPLES)      // 2048
#define HW ((size_t)512 * 512)

struct F3 { float x, y, z; };              // 12B, 4B-aligned -> dwordx3

__device__ __forceinline__ float wave_reduce_sum(float v) {
    v += __shfl_xor(v, 32, 64);
    v += __shfl_xor(v, 16, 64);
    v += __shfl_xor(v, 8, 64);
    v += __shfl_xor(v, 4, 64);
    v += __shfl_xor(v, 2, 64);
    v += __shfl_xor(v, 1, 64);
    return v;
}

// Phase 1: block = (b,c) image pair, thread = sample. Wave lanes hit 64
// RANDOM positions in one 1MB image -> no 2^20-stride aliasing. Writes the
// 16 center-diffs per (b,c,s) as one coalesced 64B segment.
__global__ void __launch_bounds__(256)
gather_kernel(const float* __restrict__ fq, const float* __restrict__ fk,
              const int* __restrict__ ids, float* __restrict__ wsd) {
    const int bc = blockIdx.x;             // b*64 + c
    const int s  = threadIdx.x;            // sample
    const int hi = ids[2 * s + 0];
    const int wi = ids[2 * s + 1];
    const size_t base = (size_t)bc * HW + (size_t)hi * IMG_W + wi;

    const F3 q0 = *(const F3*)(fq + base);
    const F3 q1 = *(const F3*)(fq + base + IMG_W);
    const F3 q2 = *(const F3*)(fq + base + 2 * IMG_W);
    const F3 k0 = *(const F3*)(fk + base);
    const F3 k1 = *(const F3*)(fk + base + IMG_W);
    const F3 k2 = *(const F3*)(fk + base + 2 * IMG_W);

    const float qc = q1.y, kc = k1.y;      // centers (hi+1, wi+1)
    const float4 o0 = make_float4(q0.x - qc, q0.y - qc, q0.z - qc, q1.x - qc);
    const float4 o1 = make_float4(q1.z - qc, q2.x - qc, q2.y - qc, q2.z - qc);
    const float4 o2 = make_float4(k0.x - kc, k0.y - kc, k0.z - kc, k1.x - kc);
    const float4 o3 = make_float4(k1.z - kc, k2.x - kc, k2.y - kc, k2.z - kc);

    float4* dst = (float4*)wsd + ((size_t)bc * NUM_SAMPLES + s) * 4;
    dst[0] = o0; dst[1] = o1; dst[2] = o2; dst[3] = o3;
}

// Phase 2: block = (b,s), lane = channel. Each lane reads its 16 diffs as
// one contiguous 64B line (L2/L3-warm), then wave-reduce norms over channels.
__global__ void __launch_bounds__(64)
norm_kernel(const float* __restrict__ wsd, float* __restrict__ partial) {
    const int c  = threadIdx.x;            // channel
    const int bs = blockIdx.x;
    const int b  = bs >> 8;
    const int s  = bs & (NUM_SAMPLES - 1);

    const float4* src =
        (const float4*)wsd + ((size_t)(b * CH + c) * NUM_SAMPLES + s) * 4;
    const float4 a0 = src[0], a1 = src[1], a2 = src[2], a3 = src[3];
    const float qd[8] = {a0.x, a0.y, a0.z, a0.w, a1.x, a1.y, a1.z, a1.w};
    const float kd[8] = {a2.x, a2.y, a2.z, a2.w, a3.x, a3.y, a3.z, a3.w};

    float acc = 0.0f;
#pragma unroll
    for (int n = 0; n < 8; ++n) {
        const float sq = wave_reduce_sum(qd[n] * qd[n]);
        const float sk = wave_reduce_sum(kd[n] * kd[n]);
        const float qn = qd[n] * (1.0f / (sqrtf(sq) + 1e-7f));
        const float kn = kd[n] * (1.0f / (sqrtf(sk) + 1e-7f));
        acc += fabsf(qn - kn);
    }
    acc = wave_reduce_sum(acc);
    if (c == 0) partial[bs] = acc;
}

__global__ void __launch_bounds__(256)
final_reduce_kernel(const float* __restrict__ partial, float* __restrict__ out) {
    __shared__ float sm[4];
    const int t = threadIdx.x;
    const float4 v0 = ((const float4*)partial)[t * 2 + 0];
    const float4 v1 = ((const float4*)partial)[t * 2 + 1];
    float v = v0.x + v0.y + v0.z + v0.w + v1.x + v1.y + v1.z + v1.w;
    v = wave_reduce_sum(v);
    if ((t & 63) == 0) sm[t >> 6] = v;
    __syncthreads();
    if (t == 0) {
        const float tot = sm[0] + sm[1] + sm[2] + sm[3];
        // mean over B * C * NUM_SAMPLES * 8 = 1048576 elements
        out[0] = tot * (1.0f / 1048576.0f);
    }
}

extern "C" void kernel_launch(void* const* d_in, const int* in_sizes, int n_in,
                              void* d_out, int out_size, void* d_ws, size_t ws_size,
                              hipStream_t stream) {
    const float* fq  = (const float*)d_in[0];
    const float* fk  = (const float*)d_in[1];
    const int*   ids = (const int*)d_in[2];
    float* out     = (float*)d_out;
    float* wsd     = (float*)d_ws;                         // 8 MB of diffs
    float* partial = (float*)d_ws + (size_t)BATCH * CH * NUM_SAMPLES * 16;

    gather_kernel<<<BATCH * CH, NUM_SAMPLES, 0, stream>>>(fq, fk, ids, wsd);
    norm_kernel<<<NBLOCKS, 64, 0, stream>>>(wsd, partial);
    final_reduce_kernel<<<1, 256, 0, stream>>>(partial, out);
}

// Round 7
// 28.350 us; speedup vs baseline: 1.1080x; 1.1080x over previous
//
#include <hip/hip_runtime.h>
#include <hip/hip_bf16.h>

#define NUM_SAMPLES 256
#define CH 64
#define IMG_H 512
#define IMG_W 512
#define BATCH 8
#define NBLOCKS (BATCH * NUM_SAMPLES)   // 2048

__device__ __forceinline__ float wave_reduce_sum(float v) {
    v += __shfl_xor(v, 32, 64);
    v += __shfl_xor(v, 16, 64);
    v += __shfl_xor(v, 8, 64);
    v += __shfl_xor(v, 4, 64);
    v += __shfl_xor(v, 2, 64);
    v += __shfl_xor(v, 1, 64);
    return v;
}

// One block of 4 waves per (b, s): wave = (tensor, half-of-neighbors).
//   wid 0: q, nbrs 0-3   wid 1: k, nbrs 0-3
//   wid 2: q, nbrs 4-7   wid 3: k, nbrs 4-7
// Lane = channel. Q loads are normal (target: stay L2-resident across graph
// replays — per-XCD Q footprint 3.56 MiB < 4 MiB L2). K loads are
// nontemporal so they don't evict Q lines from L2.
__global__ void __launch_bounds__(256)
sample_diff_kernel(const float* __restrict__ fq,
                   const float* __restrict__ fk,
                   const int* __restrict__ ids,
                   float* __restrict__ partial) {
    const int c    = threadIdx.x & 63;   // channel 0..63
    const int wid  = threadIdx.x >> 6;   // 0..3
    const int tk   = wid & 1;            // 0 = q, 1 = k
    const int half = wid >> 1;           // 0 = neighbors 0-3, 1 = neighbors 4-7
    const int bs   = blockIdx.x;
    const int b    = bs >> 8;
    const int s    = bs & (NUM_SAMPLES - 1);

    const int hi = ids[2 * s + 0];
    const int wi = ids[2 * s + 1];

    const float* __restrict__ src = tk ? fk : fq;

    const size_t HW   = (size_t)IMG_H * IMG_W;
    const size_t base = ((size_t)(b * CH + c)) * HW + (size_t)hi * IMG_W + wi;

    size_t off[4];
    if (half == 0) {
        off[0] = 0;                 // (0,0)
        off[1] = 1;                 // (0,1)
        off[2] = 2;                 // (0,2)
        off[3] = IMG_W;             // (1,0)
    } else {
        off[0] = IMG_W + 2;         // (1,2)
        off[1] = 2 * IMG_W;         // (2,0)
        off[2] = 2 * IMG_W + 1;     // (2,1)
        off[3] = 2 * IMG_W + 2;     // (2,2)
    }

    float ctr, nb[4];
    if (tk == 0) {
        // Q: normal loads — allocate in L2, survive across replays
        ctr = src[base + IMG_W + 1];
#pragma unroll
        for (int n = 0; n < 4; ++n) nb[n] = src[base + off[n]];
    } else {
        // K: nontemporal — don't displace Q's L2 lines
        ctr = __builtin_nontemporal_load(src + base + IMG_W + 1);
#pragma unroll
        for (int n = 0; n < 4; ++n)
            nb[n] = __builtin_nontemporal_load(src + base + off[n]);
    }

    // per-neighbor diff + L2 normalization over the 64 channels
    float nv[4];
#pragma unroll
    for (int n = 0; n < 4; ++n) {
        const float d  = nb[n] - ctr;
        const float ss = wave_reduce_sum(d * d);
        nv[n] = d * (1.0f / (sqrtf(ss) + 1e-7f));
    }

    // k-waves publish normalized vectors; q-waves compute |q̂ - k̂|
    __shared__ float kx[2][4][64];       // [half][neighbor][lane]
    __shared__ float sm[2];
    if (tk == 1) {
#pragma unroll
        for (int n = 0; n < 4; ++n) kx[half][n][c] = nv[n];
    }
    __syncthreads();
    if (tk == 0) {
        float acc = 0.0f;
#pragma unroll
        for (int n = 0; n < 4; ++n) acc += fabsf(nv[n] - kx[half][n][c]);
        acc = wave_reduce_sum(acc);
        if (c == 0) sm[half] = acc;
    }
    __syncthreads();
    if (threadIdx.x == 0) partial[bs] = sm[0] + sm[1];
}

__global__ void __launch_bounds__(64)
final_reduce_kernel(const float* __restrict__ partial, float* __restrict__ out) {
    const int c = threadIdx.x;
    float v = 0.0f;
#pragma unroll
    for (int i = 0; i < NBLOCKS / 64; ++i)   // 32 per lane, fixed order
        v += partial[i * 64 + c];
    v = wave_reduce_sum(v);
    if (c == 0) {
        // mean over B * C * NUM_SAMPLES * 8 = 1048576 elements
        out[0] = v * (1.0f / 1048576.0f);
    }
}

extern "C" void kernel_launch(void* const* d_in, const int* in_sizes, int n_in,
                              void* d_out, int out_size, void* d_ws, size_t ws_size,
                              hipStream_t stream) {
    const float* fq  = (const float*)d_in[0];
    const float* fk  = (const float*)d_in[1];
    const int*   ids = (const int*)d_in[2];
    float* out     = (float*)d_out;
    float* partial = (float*)d_ws;   // 2048 * 4 = 8 KB

    sample_diff_kernel<<<NBLOCKS, 256, 0, stream>>>(fq, fk, ids, partial);
    final_reduce_kernel<<<1, 64, 0, stream>>>(partial, out);
}